// Round 3
// baseline (272.051 us; speedup 1.0000x reference)
//
#include <hip/hip_runtime.h>

// AvgSeq: out[b,s,d] = (sum_{t<=s} x[b,t,d]) / (s+1)
// x: [16, 8192, 256] float32
//
// Single-pass decoupled-lookback chunked scan (rocPRIM/CUB pattern):
//   - 4096 single-wave blocks, one per (b, chunk of 32 rows); lane = float4 col
//   - phase 1: chunk sum (16-deep load batches)
//   - publish aggregate -> lookback over predecessors -> publish inclusive
//   - phase 2: rescan own chunk from cache, nontemporal store of out
// Co-residency: <=128 VGPR -> 16 waves/CU -> all 4096 blocks resident; a block
// only waits on LOWER block ids, so no deadlock even under partial residency.
#define BB 16
#define SS 8192
#define DD 256
#define D4 (DD / 4)       // 64 float4 columns = one wave
#define NC 256            // chunks along S
#define CL (SS / NC)      // 32 rows per chunk
#define G  16             // load-batch depth (16 KB in flight per wave)

#define NBLK (BB * NC)                       // 4096
#define AGGA_OFF (64 * 1024)                 // flags occupy [0, 16KB)
#define AGG_BYTES (NBLK * DD * 4)            // 4 MiB per table
#define AGGI_OFF (AGGA_OFF + AGG_BYTES)
#define WS_NEEDED ((size_t)(AGGI_OFF + AGG_BYTES))

typedef float nat4 __attribute__((ext_vector_type(4)));  // native vec for nontemporal builtin

union F2U { float2 f; unsigned long long u; };

__global__ __launch_bounds__(256) void avgseq_init(int* __restrict__ flags) {
    const int i = blockIdx.x * 256 + threadIdx.x;
    if (i < NBLK) flags[i] = 0;
}

__global__ __launch_bounds__(64, 4) void avgseq_lookback(
    const float4* __restrict__ x, float4* __restrict__ out,
    int* __restrict__ flags, unsigned long long* __restrict__ aggA,
    unsigned long long* __restrict__ aggI)
{
    const int blk = blockIdx.x;          // b*NC + c
    const int b = blk >> 8;
    const int c = blk & (NC - 1);
    const int t = threadIdx.x;

    const size_t base = ((size_t)b * SS + (size_t)c * CL) * D4 + t;
    const float4* p = x + base;

    // ---- phase 1: chunk sum ----
    float4 agg = make_float4(0.f, 0.f, 0.f, 0.f);
    for (int s0 = 0; s0 < CL; s0 += G) {
        float4 v[G];
#pragma unroll
        for (int g = 0; g < G; ++g) v[g] = p[(size_t)(s0 + g) * D4];
#pragma unroll
        for (int g = 0; g < G; ++g) {
            agg.x += v[g].x; agg.y += v[g].y; agg.z += v[g].z; agg.w += v[g].w;
        }
    }

    const size_t slot = (size_t)blk * (DD / 2) + (size_t)t * 2;  // ull index

    // ---- publish aggregate (flag=1) ----
    if (c > 0) {
        F2U lo, hi;
        lo.f = make_float2(agg.x, agg.y);
        hi.f = make_float2(agg.z, agg.w);
        __hip_atomic_store(&aggA[slot],     lo.u, __ATOMIC_RELAXED, __HIP_MEMORY_SCOPE_AGENT);
        __hip_atomic_store(&aggA[slot + 1], hi.u, __ATOMIC_RELAXED, __HIP_MEMORY_SCOPE_AGENT);
        asm volatile("s_waitcnt vmcnt(0)" ::: "memory");  // HW release: data visible before flag
        __hip_atomic_store(&flags[blk], 1, __ATOMIC_RELAXED, __HIP_MEMORY_SCOPE_AGENT);
    }

    // ---- lookback: exclusive prefix of preceding chunks (f64 accumulation) ----
    double rx = 0.0, ry = 0.0, rz = 0.0, rw = 0.0;
    if (c > 0) {
        int cc = c - 1;
        for (;;) {
            const int fblk = (b << 8) + cc;
            int f;
            for (;;) {
                f = __hip_atomic_load(&flags[fblk], __ATOMIC_RELAXED, __HIP_MEMORY_SCOPE_AGENT);
                f = __builtin_amdgcn_readfirstlane(f);  // wave-uniform control
                if (f != 0) break;
                __builtin_amdgcn_s_sleep(1);
            }
            const unsigned long long* src = (f == 2) ? aggI : aggA;
            const size_t s2 = (size_t)fblk * (DD / 2) + (size_t)t * 2;
            F2U a, bq;
            a.u  = __hip_atomic_load(&src[s2],     __ATOMIC_RELAXED, __HIP_MEMORY_SCOPE_AGENT);
            bq.u = __hip_atomic_load(&src[s2 + 1], __ATOMIC_RELAXED, __HIP_MEMORY_SCOPE_AGENT);
            rx += a.f.x; ry += a.f.y; rz += bq.f.x; rw += bq.f.y;
            if (f == 2) break;   // that predecessor was inclusive: prefix complete
            --cc;
        }
    }
    const float4 run = make_float4((float)rx, (float)ry, (float)rz, (float)rw);

    // ---- publish inclusive (flag=2); last chunk has no successor ----
    if (c < NC - 1) {
        F2U lo, hi;
        lo.f = make_float2(run.x + agg.x, run.y + agg.y);
        hi.f = make_float2(run.z + agg.z, run.w + agg.w);
        __hip_atomic_store(&aggI[slot],     lo.u, __ATOMIC_RELAXED, __HIP_MEMORY_SCOPE_AGENT);
        __hip_atomic_store(&aggI[slot + 1], hi.u, __ATOMIC_RELAXED, __HIP_MEMORY_SCOPE_AGENT);
        asm volatile("s_waitcnt vmcnt(0)" ::: "memory");
        __hip_atomic_store(&flags[blk], 2, __ATOMIC_RELAXED, __HIP_MEMORY_SCOPE_AGENT);
    }

    // ---- phase 2: rescan own chunk (cache-hot) and emit means ----
    float4 acc = run;
    float4* o = out + base;
    const int sb = c * CL;
    for (int s0 = 0; s0 < CL; s0 += G) {
        float4 v[G];
#pragma unroll
        for (int g = 0; g < G; ++g) v[g] = p[(size_t)(s0 + g) * D4];
#pragma unroll
        for (int g = 0; g < G; ++g) {
            acc.x += v[g].x; acc.y += v[g].y; acc.z += v[g].z; acc.w += v[g].w;
            const float r = __builtin_amdgcn_rcpf((float)(sb + s0 + g + 1));
            v[g] = make_float4(acc.x * r, acc.y * r, acc.z * r, acc.w * r);
        }
#pragma unroll
        for (int g = 0; g < G; ++g) {
            nat4 nv = { v[g].x, v[g].y, v[g].z, v[g].w };
            __builtin_nontemporal_store(nv, (nat4*)&o[(size_t)(s0 + g) * D4]);  // out never re-read
        }
    }
}

// ---------------- fallback (verified round-1 path) if ws is too small ----------------
__global__ __launch_bounds__(64) void avgseq_chunksum(const float4* __restrict__ x,
                                                      float4* __restrict__ ws) {
    const int blk = blockIdx.x;
    const int b = blk >> 8;
    const int c = blk & (NC - 1);
    const int t = threadIdx.x;
    const float4* p = x + ((size_t)b * SS + (size_t)c * CL) * D4 + t;
    float4 acc = make_float4(0.f, 0.f, 0.f, 0.f);
    for (int s0 = 0; s0 < CL; s0 += G) {
        float4 v[G];
#pragma unroll
        for (int g = 0; g < G; ++g) v[g] = p[(size_t)(s0 + g) * D4];
#pragma unroll
        for (int g = 0; g < G; ++g) {
            acc.x += v[g].x; acc.y += v[g].y; acc.z += v[g].z; acc.w += v[g].w;
        }
    }
    ws[((size_t)b * NC + c) * D4 + t] = acc;
}

__global__ __launch_bounds__(64) void avgseq_scanws(float4* __restrict__ ws) {
    const int b = blockIdx.x;
    const int t = threadIdx.x;
    float4* w = ws + (size_t)b * NC * D4 + t;
    float4 run = make_float4(0.f, 0.f, 0.f, 0.f);
#pragma unroll 8
    for (int c = 0; c < NC; ++c) {
        float4 v = w[(size_t)c * D4];
        w[(size_t)c * D4] = run;
        run.x += v.x; run.y += v.y; run.z += v.z; run.w += v.w;
    }
}

__global__ __launch_bounds__(64) void avgseq_scan(const float4* __restrict__ x,
                                                  const float4* __restrict__ ws,
                                                  float4* __restrict__ out) {
    const int blk = blockIdx.x;
    const int b = blk >> 8;
    const int c = blk & (NC - 1);
    const int t = threadIdx.x;
    float4 acc = ws[((size_t)b * NC + c) * D4 + t];
    const size_t base = ((size_t)b * SS + (size_t)c * CL) * D4 + t;
    const float4* p = x + base;
    float4* o = out + base;
    const int s0 = c * CL;
    for (int ss = 0; ss < CL; ss += G) {
        float4 v[G];
#pragma unroll
        for (int g = 0; g < G; ++g) v[g] = p[(size_t)(ss + g) * D4];
#pragma unroll
        for (int g = 0; g < G; ++g) {
            acc.x += v[g].x; acc.y += v[g].y; acc.z += v[g].z; acc.w += v[g].w;
            const float r = __builtin_amdgcn_rcpf((float)(s0 + ss + g + 1));
            v[g] = make_float4(acc.x * r, acc.y * r, acc.z * r, acc.w * r);
        }
#pragma unroll
        for (int g = 0; g < G; ++g) o[(size_t)(ss + g) * D4] = v[g];
    }
}

extern "C" void kernel_launch(void* const* d_in, const int* in_sizes, int n_in,
                              void* d_out, int out_size, void* d_ws, size_t ws_size,
                              hipStream_t stream) {
    const float4* x = (const float4*)d_in[0];
    float4* out = (float4*)d_out;

    if (ws_size >= WS_NEEDED) {
        int* flags = (int*)d_ws;
        unsigned long long* aggA = (unsigned long long*)((char*)d_ws + AGGA_OFF);
        unsigned long long* aggI = (unsigned long long*)((char*)d_ws + AGGI_OFF);
        avgseq_init<<<(NBLK + 255) / 256, 256, 0, stream>>>(flags);
        avgseq_lookback<<<NBLK, 64, 0, stream>>>(x, out, flags, aggA, aggI);
    } else {
        float4* ws = (float4*)d_ws;
        avgseq_chunksum<<<NBLK, 64, 0, stream>>>(x, ws);
        avgseq_scanws<<<BB, 64, 0, stream>>>(ws);
        avgseq_scan<<<NBLK, 64, 0, stream>>>(x, ws, out);
    }
}